// Round 12
// baseline (568.446 us; speedup 1.0000x reference)
//
#include <hip/hip_runtime.h>

// Problem constants
#define B_    4
#define N_    16384
#define D_    64
#define Q_    128
#define E_    131072
#define M_    4
#define BN    65536        // B*N
#define TOTE  524288       // B*E
#define ITERS 25
#define PAD_CAP (TOTE + 3 * BN + 64)   // padded-CSR capacity (edges)

// Output layout (f32, concatenated flat):
//   nf:         (4,5,64)      = 1280   @ 0
//   masks_ext:  (4,5,128,128) = 327680 @ 1280
//   node_scores:(4,5)         = 20     @ 328960
#define OFF_MASKS 1280
#define OFF_SCORES 328960

__constant__ int c_agidx[4] = {0, 5461, 10922, 16383};

// pack two f32 -> (bf16,bf16) in one uint, RTNE
__device__ __forceinline__ unsigned pack_bf16x2(float x, float y) {
    unsigned ux = __float_as_uint(x);
    unsigned uy = __float_as_uint(y);
    ux = (ux + 0x7fffu + ((ux >> 16) & 1u)) >> 16;          // low 16 = bf16(x)
    uy = (uy + 0x7fffu + ((uy >> 16) & 1u)) & 0xffff0000u;  // high 16 = bf16(y)
    return ux | uy;
}

// ---------- CSR build ----------
__global__ void k_count(const int* __restrict__ edges, const float* __restrict__ wts,
                        int* __restrict__ deg) {
    int idx = blockIdx.x * blockDim.x + threadIdx.x;
    if (idx >= TOTE) return;
    int b = idx >> 17;           // / E_
    int e = idx & (E_ - 1);
    float w = wts[idx];          // (B,E) flat == idx
    if (w > 0.5f) {
        int row = edges[(b * 2) * E_ + e];
        atomicAdd(&deg[row], 1);
    }
}

// ---- parallel scan over padded degrees ----
__global__ __launch_bounds__(256) void k_scan1(const int* __restrict__ deg,
                                               int* __restrict__ blockSums) {
    int i = blockIdx.x * 256 + threadIdx.x;
    int v = (deg[i] + 3) & ~3;
    #pragma unroll
    for (int off = 1; off < 64; off <<= 1) v += __shfl_xor(v, off, 64);
    __shared__ int ws[4];
    int lane = threadIdx.x & 63, w = threadIdx.x >> 6;
    if (lane == 0) ws[w] = v;
    __syncthreads();
    if (threadIdx.x == 0)
        blockSums[blockIdx.x] = ws[0] + ws[1] + ws[2] + ws[3];
}

// each block redundantly scans the 256 block sums, then rescans its 256 rows
__global__ __launch_bounds__(256) void k_scan3(const int* __restrict__ deg,
                                               const int* __restrict__ blockSums,
                                               int* __restrict__ row_start,
                                               int* __restrict__ cursor) {
    int t = threadIdx.x;
    int lane = t & 63, w = t >> 6;
    __shared__ int offs[256];
    __shared__ int wtotA[4];
    __shared__ int wtotB[4];

    int bs = blockSums[t];
    int binc = bs;
    #pragma unroll
    for (int off = 1; off < 64; off <<= 1) {
        int u = __shfl_up(binc, off, 64);
        if (lane >= off) binc += u;
    }
    if (lane == 63) wtotA[w] = binc;
    __syncthreads();
    int badd = 0;
    for (int j = 0; j < w; ++j) badd += wtotA[j];
    offs[t] = binc + badd - bs;
    if (blockIdx.x == 0 && t == 255) row_start[BN] = binc + badd;
    __syncthreads();
    int blockOff = offs[blockIdx.x];

    int i = blockIdx.x * 256 + t;
    int v = (deg[i] + 3) & ~3;
    int incl = v;
    #pragma unroll
    for (int off = 1; off < 64; off <<= 1) {
        int u = __shfl_up(incl, off, 64);
        if (lane >= off) incl += u;
    }
    if (lane == 63) wtotB[w] = incl;
    __syncthreads();
    int wadd = 0;
    for (int j = 0; j < w; ++j) wadd += wtotB[j];
    int rs = blockOff + wadd + incl - v;
    row_start[i] = rs;
    cursor[i] = rs;
}

__global__ void k_scatter(const int* __restrict__ edges, const float* __restrict__ wts,
                          int* __restrict__ cursor, int2* __restrict__ cw) {
    int idx = blockIdx.x * blockDim.x + threadIdx.x;
    if (idx >= TOTE) return;
    int b = idx >> 17;
    int e = idx & (E_ - 1);
    float w = wts[idx];
    if (w > 0.5f) {
        int row = edges[(b * 2) * E_ + e];
        int col = edges[(b * 2) * E_ + E_ + e];
        int pos = atomicAdd(&cursor[row], 1);
        cw[pos] = make_int2(col, __float_as_int(w));
    }
}

// Deterministic order within each row's REAL segment: sort by (col, w-bits).
// Also writes the (0,0) padding entries up to the 4-aligned row end.
__global__ void k_sort(const int* __restrict__ row_start, const int* __restrict__ deg,
                       int2* __restrict__ cw) {
    int n = blockIdx.x * blockDim.x + threadIdx.x;
    if (n >= BN) return;
    int s = row_start[n], epos = s + deg[n], pend = row_start[n + 1];
    for (int i = s + 1; i < epos; ++i) {
        int2 v = cw[i];
        unsigned long long key =
            ((unsigned long long)(unsigned)v.x << 32) | (unsigned)v.y;
        int j = i - 1;
        while (j >= s) {
            int2 u = cw[j];
            unsigned long long kj =
                ((unsigned long long)(unsigned)u.x << 32) | (unsigned)u.y;
            if (kj <= key) break;
            cw[j + 1] = u;
            --j;
        }
        cw[j + 1] = v;
    }
    for (int i = epos; i < pend; ++i) cw[i] = make_int2(0, 0);
}

// ---------- propagation: TWO nodes per wave (g and g+32768) ----------
// 8 gathers in flight per wave (empirically saturating for this access
// pattern). Per-row arithmetic bit-exact (sorted edge order; shorter node's
// last chunk replays with w=0).
template <bool F32IN>
__global__ __launch_bounds__(256) void k_prop(const void* __restrict__ hin,
                                              unsigned* __restrict__ hout,
                                              const int* __restrict__ row_start,
                                              const int2* __restrict__ cw) {
    int lane = threadIdx.x & 63;
    int gid = (blockIdx.x << 2) + (threadIdx.x >> 6);   // 0..32767
    int uA = __builtin_amdgcn_readfirstlane(gid);
    int uB = uA + 32768;
    int sA = row_start[uA], eA = row_start[uA + 1];
    int sB = row_start[uB], eB = row_start[uB + 1];
    int cA = (eA - sA) >> 2, cB = (eB - sB) >> 2;
    int nmax = cA > cB ? cA : cB;
    int baseA = cA ? sA : sB;
    int baseB = cB ? sB : sA;
    int lastA = (cA ? cA : 1) - 1;
    int lastB = (cB ? cB : 1) - 1;

    auto gather = [&](int col) -> float2 {
        if constexpr (F32IN) {
            return ((const float2*)hin)[((size_t)col << 6) + lane];
        } else {
            unsigned p = ((const unsigned*)hin)[((size_t)col << 6) + lane];
            float2 r;
            r.x = __uint_as_float(p << 16);
            r.y = __uint_as_float(p & 0xffff0000u);
            return r;
        }
    };

    float axA = 0.f, ayA = 0.f, axB = 0.f, ayB = 0.f;
    for (int j = 0; j < nmax; ++j) {
        int jA = j < lastA ? j : lastA;
        int jB = j < lastB ? j : lastB;
        const int4* qA = (const int4*)(cw + baseA + (jA << 2));
        const int4* qB = (const int4*)(cw + baseB + (jB << 2));
        int4 a0 = qA[0], a1 = qA[1];
        int4 b0 = qB[0], b1 = qB[1];
        float2 vA0 = gather(a0.x);
        float2 vA1 = gather(a0.z);
        float2 vA2 = gather(a1.x);
        float2 vA3 = gather(a1.z);
        float2 vB0 = gather(b0.x);
        float2 vB1 = gather(b0.z);
        float2 vB2 = gather(b1.x);
        float2 vB3 = gather(b1.z);
        bool okA = j < cA, okB = j < cB;
        float wA0 = okA ? __int_as_float(a0.y) : 0.f;
        float wA1 = okA ? __int_as_float(a0.w) : 0.f;
        float wA2 = okA ? __int_as_float(a1.y) : 0.f;
        float wA3 = okA ? __int_as_float(a1.w) : 0.f;
        float wB0 = okB ? __int_as_float(b0.y) : 0.f;
        float wB1 = okB ? __int_as_float(b0.w) : 0.f;
        float wB2 = okB ? __int_as_float(b1.y) : 0.f;
        float wB3 = okB ? __int_as_float(b1.w) : 0.f;
        axA = fmaf(wA0, vA0.x, axA); ayA = fmaf(wA0, vA0.y, ayA);
        axA = fmaf(wA1, vA1.x, axA); ayA = fmaf(wA1, vA1.y, ayA);
        axA = fmaf(wA2, vA2.x, axA); ayA = fmaf(wA2, vA2.y, ayA);
        axA = fmaf(wA3, vA3.x, axA); ayA = fmaf(wA3, vA3.y, ayA);
        axB = fmaf(wB0, vB0.x, axB); ayB = fmaf(wB0, vB0.y, ayB);
        axB = fmaf(wB1, vB1.x, axB); ayB = fmaf(wB1, vB1.y, ayB);
        axB = fmaf(wB2, vB2.x, axB); ayB = fmaf(wB2, vB2.y, ayB);
        axB = fmaf(wB3, vB3.x, axB); ayB = fmaf(wB3, vB3.y, ayB);
    }
    float ssA = axA * axA + ayA * ayA;
    float ssB = axB * axB + ayB * ayB;
    #pragma unroll
    for (int off = 32; off; off >>= 1) {
        ssA += __shfl_xor(ssA, off, 64);
        ssB += __shfl_xor(ssB, off, 64);
    }
    float invA = 1.0f / (sqrtf(ssA) + 1e-8f);
    float invB = 1.0f / (sqrtf(ssB) + 1e-8f);
    hout[((size_t)uA << 6) + lane] = pack_bf16x2(axA * invA, ayA * invA);
    hout[((size_t)uB << 6) + lane] = pack_bf16x2(axB * invB, ayB * invB);
}

// ---------- fused epilogue: masks softmax + nf partials + chunk maxes ----------
// grid: 4 b x 64 chunks = 256 blocks; each block covers 256 rows.
// Agent rows staged in LDS once per block; per row: dot with 4 agents
// (full-butterfly shfl_xor -> lane-uniform sums), 5-way softmax, masks
// write, nf partial fma, running max. Deterministic (no atomics).
__global__ __launch_bounds__(256) void k_masksnf(const unsigned* __restrict__ h,
                                                 const float* __restrict__ feat,
                                                 float* __restrict__ masks,
                                                 float* __restrict__ part,
                                                 float* __restrict__ maxpart) {
    int b = blockIdx.x >> 6;
    int chunk = blockIdx.x & 63;
    int g = threadIdx.x >> 6;   // wave 0..3
    int lane = threadIdx.x & 63;

    __shared__ unsigned ag[4][64];
    ag[g][lane] = h[((size_t)(b * N_ + c_agidx[g]) << 6) + lane];
    __syncthreads();
    float amx[4], amy[4];
    #pragma unroll
    for (int m = 0; m < 4; ++m) {
        unsigned ap = ag[m][lane];
        amx[m] = __uint_as_float(ap << 16);
        amy[m] = __uint_as_float(ap & 0xffff0000u);
    }

    const float* fb = feat + (size_t)b * N_ * D_;
    const float scl = 0.0883883476483184405501055452631f; // 1/sqrt(128)
    int n0 = chunk * 256 + g * 64;
    float acc[5] = {0.f, 0.f, 0.f, 0.f, 0.f};
    float mxv[5] = {-1e30f, -1e30f, -1e30f, -1e30f, -1e30f};

    for (int i = 0; i < 64; ++i) {
        int n = n0 + i;                                   // row within batch b
        unsigned vp = h[((size_t)(b * N_ + n) << 6) + lane];
        float vx = __uint_as_float(vp << 16);
        float vy = __uint_as_float(vp & 0xffff0000u);
        float d0 = vx * amx[0] + vy * amy[0];
        float d1 = vx * amx[1] + vy * amy[1];
        float d2 = vx * amx[2] + vy * amy[2];
        float d3 = vx * amx[3] + vy * amy[3];
        #pragma unroll
        for (int off = 32; off; off >>= 1) {
            d0 += __shfl_xor(d0, off, 64);
            d1 += __shfl_xor(d1, off, 64);
            d2 += __shfl_xor(d2, off, 64);
            d3 += __shfl_xor(d3, off, 64);
        }
        float l0 = d0 * scl, l1 = d1 * scl, l2 = d2 * scl, l3 = d3 * scl;
        float mx = fmaxf(fmaxf(fmaxf(l0, l1), fmaxf(l2, l3)), 0.f);
        float e0 = expf(l0 - mx), e1 = expf(l1 - mx), e2 = expf(l2 - mx),
              e3 = expf(l3 - mx), e4 = expf(0.f - mx);
        float rden = 1.0f / (e0 + e1 + e2 + e3 + e4);
        float p0 = e0 * rden, p1 = e1 * rden, p2 = e2 * rden,
              p3 = e3 * rden, p4 = e4 * rden;
        if (lane < 5) {
            float p = (lane == 0) ? p0 : (lane == 1) ? p1 : (lane == 2) ? p2
                      : (lane == 3) ? p3 : p4;
            masks[((size_t)b * 5 + lane) * N_ + n] = p;
        }
        float fv = fb[(size_t)n * D_ + lane];
        acc[0] = fmaf(fv, p0, acc[0]);
        acc[1] = fmaf(fv, p1, acc[1]);
        acc[2] = fmaf(fv, p2, acc[2]);
        acc[3] = fmaf(fv, p3, acc[3]);
        acc[4] = fmaf(fv, p4, acc[4]);
        mxv[0] = fmaxf(mxv[0], p0);
        mxv[1] = fmaxf(mxv[1], p1);
        mxv[2] = fmaxf(mxv[2], p2);
        mxv[3] = fmaxf(mxv[3], p3);
        mxv[4] = fmaxf(mxv[4], p4);
    }

    __shared__ float lds[4][5][64];
    __shared__ float lmx[4][5];
    #pragma unroll
    for (int m = 0; m < 5; ++m) lds[g][m][lane] = acc[m];
    if (lane == 0) {
        #pragma unroll
        for (int m = 0; m < 5; ++m) lmx[g][m] = mxv[m];
    }
    __syncthreads();
    if (g == 0) {
        #pragma unroll
        for (int m = 0; m < 5; ++m) {
            float s = lds[0][m][lane] + lds[1][m][lane] + lds[2][m][lane] + lds[3][m][lane];
            part[(((size_t)b * 64 + chunk) * 5 + m) * 64 + lane] = s;
            if (lane == 0)
                maxpart[((size_t)b * 64 + chunk) * 5 + m] =
                    fmaxf(fmaxf(lmx[0][m], lmx[1][m]), fmaxf(lmx[2][m], lmx[3][m]));
        }
    }
}

// ---------- final: sum chunks, normalize over m-axis, scores ----------
__global__ void k_nffinal(const float* __restrict__ part, const float* __restrict__ maxpart,
                          float* __restrict__ out) {
    int b = blockIdx.x;     // 4 blocks
    int d = threadIdx.x;    // 64 threads
    float v[5];
    float ss = 0.f;
    for (int m = 0; m < 5; ++m) {
        float s = 0.f;
        for (int c = 0; c < 64; ++c)
            s += part[(((size_t)b * 64 + c) * 5 + m) * 64 + d];
        v[m] = s;
        ss += s * s;
    }
    float nrm = fmaxf(sqrtf(ss), 1e-12f);
    for (int m = 0; m < 5; ++m) out[((size_t)b * 5 + m) * 64 + d] = v[m] / nrm;
    if (d < 5) {
        float mx = -1e30f;
        for (int c = 0; c < 64; ++c)
            mx = fmaxf(mx, maxpart[((size_t)b * 64 + c) * 5 + d]);
        out[OFF_SCORES + b * 5 + d] = mx;
    }
}

extern "C" void kernel_launch(void* const* d_in, const int* in_sizes, int n_in,
                              void* d_out, int out_size, void* d_ws, size_t ws_size,
                              hipStream_t stream) {
    const float* feat  = (const float*)d_in[0];   // (4,16384,64)
    const int*   edges = (const int*)d_in[1];     // (4,2,131072)
    const float* wts   = (const float*)d_in[2];   // (4,131072)
    const float* init  = (const float*)d_in[3];   // (4,16384,128)
    float* out = (float*)d_out;

    // workspace layout (bf16 h: 65536 rows x 64 uints = 16 MB each)
    unsigned* hA = (unsigned*)d_ws;
    unsigned* hB = hA + (size_t)BN * 64;
    int* row_start  = (int*)(hB + (size_t)BN * 64);   // 65537 (+pad)
    int* cursor     = row_start + 65544;              // 65536
    int* deg        = cursor + BN;                    // 65536
    int* blockSums  = deg + BN;                       // 256
    int2* cw        = (int2*)(blockSums + 256);       // PAD_CAP int2 (~5.8 MB)
    float* part     = (float*)(cw + PAD_CAP);         // 4*64*5*64 = 81920
    float* maxpart  = part + 81920;                   // 1280

    // CSR build (padded rows, interleaved (col,w) pairs; padding written by k_sort)
    hipMemsetAsync(deg, 0, BN * sizeof(int), stream);
    k_count<<<TOTE / 256, 256, 0, stream>>>(edges, wts, deg);
    k_scan1<<<256, 256, 0, stream>>>(deg, blockSums);
    k_scan3<<<256, 256, 0, stream>>>(deg, blockSums, row_start, cursor);
    k_scatter<<<TOTE / 256, 256, 0, stream>>>(edges, wts, cursor, cw);
    k_sort<<<BN / 256, 256, 0, stream>>>(row_start, deg, cw);

    // 25 propagation iterations; iter 0 reads f32 init directly
    k_prop<true><<<BN / 8, 256, 0, stream>>>(init, hA, row_start, cw);
    const unsigned* src = hA;
    for (int it = 1; it < ITERS; ++it) {
        unsigned* dst = (it & 1) ? hB : hA;
        k_prop<false><<<BN / 8, 256, 0, stream>>>(src, dst, row_start, cw);
        src = dst;
    }

    // fused epilogue + final
    k_masksnf<<<4 * 64, 256, 0, stream>>>(src, feat, out + OFF_MASKS, part, maxpart);
    k_nffinal<<<4, 64, 0, stream>>>(part, maxpart, out);
}

// Round 13
// 506.819 us; speedup vs baseline: 1.1216x; 1.1216x over previous
//
#include <hip/hip_runtime.h>

// Problem constants
#define B_    4
#define N_    16384
#define D_    64
#define Q_    128
#define E_    131072
#define M_    4
#define BN    65536        // B*N
#define TOTE  524288       // B*E
#define ITERS 25
#define PAD_CAP (TOTE + 3 * BN + 64)   // padded-CSR capacity (edges)

// Output layout (f32, concatenated flat):
//   nf:         (4,5,64)      = 1280   @ 0
//   masks_ext:  (4,5,128,128) = 327680 @ 1280
//   node_scores:(4,5)         = 20     @ 328960
#define OFF_MASKS 1280
#define OFF_SCORES 328960

__constant__ int c_agidx[4] = {0, 5461, 10922, 16383};

// pack two f32 -> (bf16,bf16) in one uint, RTNE
__device__ __forceinline__ unsigned pack_bf16x2(float x, float y) {
    unsigned ux = __float_as_uint(x);
    unsigned uy = __float_as_uint(y);
    ux = (ux + 0x7fffu + ((ux >> 16) & 1u)) >> 16;          // low 16 = bf16(x)
    uy = (uy + 0x7fffu + ((uy >> 16) & 1u)) & 0xffff0000u;  // high 16 = bf16(y)
    return ux | uy;
}

// ---------- CSR build ----------
__global__ void k_count(const int* __restrict__ edges, const float* __restrict__ wts,
                        int* __restrict__ deg) {
    int idx = blockIdx.x * blockDim.x + threadIdx.x;
    if (idx >= TOTE) return;
    int b = idx >> 17;           // / E_
    int e = idx & (E_ - 1);
    float w = wts[idx];          // (B,E) flat == idx
    if (w > 0.5f) {
        int row = edges[(b * 2) * E_ + e];
        atomicAdd(&deg[row], 1);
    }
}

// ---- parallel scan over padded degrees: 2 kernels ----
__global__ __launch_bounds__(256) void k_scan1(const int* __restrict__ deg,
                                               int* __restrict__ blockSums) {
    int i = blockIdx.x * 256 + threadIdx.x;
    int v = (deg[i] + 3) & ~3;
    #pragma unroll
    for (int off = 1; off < 64; off <<= 1) v += __shfl_xor(v, off, 64);
    __shared__ int ws[4];
    int lane = threadIdx.x & 63, w = threadIdx.x >> 6;
    if (lane == 0) ws[w] = v;
    __syncthreads();
    if (threadIdx.x == 0)
        blockSums[blockIdx.x] = ws[0] + ws[1] + ws[2] + ws[3];
}

// each block redundantly scans the 256 block sums, then rescans its 256 rows
__global__ __launch_bounds__(256) void k_scan3(const int* __restrict__ deg,
                                               const int* __restrict__ blockSums,
                                               int* __restrict__ row_start,
                                               int* __restrict__ cursor) {
    int t = threadIdx.x;
    int lane = t & 63, w = t >> 6;
    __shared__ int offs[256];
    __shared__ int wtotA[4];
    __shared__ int wtotB[4];

    int bs = blockSums[t];
    int binc = bs;
    #pragma unroll
    for (int off = 1; off < 64; off <<= 1) {
        int u = __shfl_up(binc, off, 64);
        if (lane >= off) binc += u;
    }
    if (lane == 63) wtotA[w] = binc;
    __syncthreads();
    int badd = 0;
    for (int j = 0; j < w; ++j) badd += wtotA[j];
    offs[t] = binc + badd - bs;        // exclusive prefix of blockSums
    if (blockIdx.x == 0 && t == 255) row_start[BN] = binc + badd;
    __syncthreads();
    int blockOff = offs[blockIdx.x];

    int i = blockIdx.x * 256 + t;
    int v = (deg[i] + 3) & ~3;
    int incl = v;
    #pragma unroll
    for (int off = 1; off < 64; off <<= 1) {
        int u = __shfl_up(incl, off, 64);
        if (lane >= off) incl += u;
    }
    if (lane == 63) wtotB[w] = incl;
    __syncthreads();
    int wadd = 0;
    for (int j = 0; j < w; ++j) wadd += wtotB[j];
    int rs = blockOff + wadd + incl - v;
    row_start[i] = rs;
    cursor[i] = rs;
}

__global__ void k_scatter(const int* __restrict__ edges, const float* __restrict__ wts,
                          int* __restrict__ cursor, int2* __restrict__ cw) {
    int idx = blockIdx.x * blockDim.x + threadIdx.x;
    if (idx >= TOTE) return;
    int b = idx >> 17;
    int e = idx & (E_ - 1);
    float w = wts[idx];
    if (w > 0.5f) {
        int row = edges[(b * 2) * E_ + e];
        int col = edges[(b * 2) * E_ + E_ + e];
        int pos = atomicAdd(&cursor[row], 1);
        cw[pos] = make_int2(col, __float_as_int(w));
    }
}

// Deterministic order within each row's REAL segment: sort by (col, w-bits).
// Also writes the (0,0) padding entries up to the 4-aligned row end.
__global__ void k_sort(const int* __restrict__ row_start, const int* __restrict__ deg,
                       int2* __restrict__ cw) {
    int n = blockIdx.x * blockDim.x + threadIdx.x;
    if (n >= BN) return;
    int s = row_start[n], epos = s + deg[n], pend = row_start[n + 1];
    for (int i = s + 1; i < epos; ++i) {
        int2 v = cw[i];
        unsigned long long key =
            ((unsigned long long)(unsigned)v.x << 32) | (unsigned)v.y;
        int j = i - 1;
        while (j >= s) {
            int2 u = cw[j];
            unsigned long long kj =
                ((unsigned long long)(unsigned)u.x << 32) | (unsigned)u.y;
            if (kj <= key) break;
            cw[j + 1] = u;
            --j;
        }
        cw[j + 1] = v;
    }
    for (int i = epos; i < pend; ++i) cw[i] = make_int2(0, 0);
}

// ---------- propagation: TWO nodes per wave (g and g+32768) ----------
// 8 gathers in flight per wave (empirically saturating for this access
// pattern). Per-row arithmetic bit-exact (sorted edge order; shorter node's
// last chunk replays with w=0).
template <bool F32IN>
__global__ __launch_bounds__(256) void k_prop(const void* __restrict__ hin,
                                              unsigned* __restrict__ hout,
                                              const int* __restrict__ row_start,
                                              const int2* __restrict__ cw) {
    int lane = threadIdx.x & 63;
    int gid = (blockIdx.x << 2) + (threadIdx.x >> 6);   // 0..32767
    int uA = __builtin_amdgcn_readfirstlane(gid);
    int uB = uA + 32768;
    int sA = row_start[uA], eA = row_start[uA + 1];
    int sB = row_start[uB], eB = row_start[uB + 1];
    int cA = (eA - sA) >> 2, cB = (eB - sB) >> 2;       // 4-edge chunk counts
    int nmax = cA > cB ? cA : cB;
    int baseA = cA ? sA : sB;    // alias empty row to the other's chunk (w=0)
    int baseB = cB ? sB : sA;
    int lastA = (cA ? cA : 1) - 1;
    int lastB = (cB ? cB : 1) - 1;

    auto gather = [&](int col) -> float2 {
        if constexpr (F32IN) {
            return ((const float2*)hin)[((size_t)col << 6) + lane];
        } else {
            unsigned p = ((const unsigned*)hin)[((size_t)col << 6) + lane];
            float2 r;
            r.x = __uint_as_float(p << 16);
            r.y = __uint_as_float(p & 0xffff0000u);
            return r;
        }
    };

    float axA = 0.f, ayA = 0.f, axB = 0.f, ayB = 0.f;
    for (int j = 0; j < nmax; ++j) {
        int jA = j < lastA ? j : lastA;
        int jB = j < lastB ? j : lastB;
        const int4* qA = (const int4*)(cw + baseA + (jA << 2));
        const int4* qB = (const int4*)(cw + baseB + (jB << 2));
        int4 a0 = qA[0], a1 = qA[1];
        int4 b0 = qB[0], b1 = qB[1];
        // 8 gathers in flight
        float2 vA0 = gather(a0.x);
        float2 vA1 = gather(a0.z);
        float2 vA2 = gather(a1.x);
        float2 vA3 = gather(a1.z);
        float2 vB0 = gather(b0.x);
        float2 vB1 = gather(b0.z);
        float2 vB2 = gather(b1.x);
        float2 vB3 = gather(b1.z);
        bool okA = j < cA, okB = j < cB;
        float wA0 = okA ? __int_as_float(a0.y) : 0.f;
        float wA1 = okA ? __int_as_float(a0.w) : 0.f;
        float wA2 = okA ? __int_as_float(a1.y) : 0.f;
        float wA3 = okA ? __int_as_float(a1.w) : 0.f;
        float wB0 = okB ? __int_as_float(b0.y) : 0.f;
        float wB1 = okB ? __int_as_float(b0.w) : 0.f;
        float wB2 = okB ? __int_as_float(b1.y) : 0.f;
        float wB3 = okB ? __int_as_float(b1.w) : 0.f;
        axA = fmaf(wA0, vA0.x, axA); ayA = fmaf(wA0, vA0.y, ayA);
        axA = fmaf(wA1, vA1.x, axA); ayA = fmaf(wA1, vA1.y, ayA);
        axA = fmaf(wA2, vA2.x, axA); ayA = fmaf(wA2, vA2.y, ayA);
        axA = fmaf(wA3, vA3.x, axA); ayA = fmaf(wA3, vA3.y, ayA);
        axB = fmaf(wB0, vB0.x, axB); ayB = fmaf(wB0, vB0.y, ayB);
        axB = fmaf(wB1, vB1.x, axB); ayB = fmaf(wB1, vB1.y, ayB);
        axB = fmaf(wB2, vB2.x, axB); ayB = fmaf(wB2, vB2.y, ayB);
        axB = fmaf(wB3, vB3.x, axB); ayB = fmaf(wB3, vB3.y, ayB);
    }
    float ssA = axA * axA + ayA * ayA;
    float ssB = axB * axB + ayB * ayB;
    #pragma unroll
    for (int off = 32; off; off >>= 1) {
        ssA += __shfl_xor(ssA, off, 64);
        ssB += __shfl_xor(ssB, off, 64);
    }
    float invA = 1.0f / (sqrtf(ssA) + 1e-8f);
    float invB = 1.0f / (sqrtf(ssB) + 1e-8f);
    hout[((size_t)uA << 6) + lane] = pack_bf16x2(axA * invA, ayA * invA);
    hout[((size_t)uB << 6) + lane] = pack_bf16x2(axB * invB, ayB * invB);
}

// ---------- competition: wave per row (bf16 h) ----------
__global__ __launch_bounds__(256) void k_masks(const unsigned* __restrict__ h,
                                               float* __restrict__ masks) {
    int wave = threadIdx.x >> 6;
    int lane = threadIdx.x & 63;
    int n = blockIdx.x * 4 + wave;      // global row 0..65535
    int b = n >> 14;
    int nl = n & (N_ - 1);
    unsigned vp = h[((size_t)n << 6) + lane];
    float vx = __uint_as_float(vp << 16);
    float vy = __uint_as_float(vp & 0xffff0000u);
    float dot[4];
    #pragma unroll
    for (int m = 0; m < 4; ++m) {
        int an = b * N_ + c_agidx[m];
        unsigned ap = h[((size_t)an << 6) + lane];
        float axx = __uint_as_float(ap << 16);
        float ayy = __uint_as_float(ap & 0xffff0000u);
        float d = vx * axx + vy * ayy;
        #pragma unroll
        for (int off = 32; off; off >>= 1) d += __shfl_xor(d, off, 64);
        dot[m] = d;
    }
    const float scl = 0.0883883476483184405501055452631f; // 1/sqrt(128)
    float l0 = dot[0] * scl, l1 = dot[1] * scl, l2 = dot[2] * scl, l3 = dot[3] * scl;
    float mx = fmaxf(fmaxf(fmaxf(l0, l1), fmaxf(l2, l3)), 0.f);
    float e0 = expf(l0 - mx), e1 = expf(l1 - mx), e2 = expf(l2 - mx),
          e3 = expf(l3 - mx), e4 = expf(0.f - mx);
    float den = e0 + e1 + e2 + e3 + e4;
    if (lane < 5) {
        float p = (lane == 0) ? e0 : (lane == 1) ? e1 : (lane == 2) ? e2
                  : (lane == 3) ? e3 : e4;
        masks[((size_t)b * 5 + lane) * N_ + nl] = p / den;
    }
}

// ---------- nf partials + chunk maxes ----------
// grid: 20 (b,m) x 64 chunks; each chunk covers 256 rows
__global__ __launch_bounds__(256) void k_nfpart(const float* __restrict__ feat,
                                                const float* __restrict__ masks,
                                                float* __restrict__ part,
                                                float* __restrict__ maxpart) {
    int bm = blockIdx.x >> 6;   // 0..19
    int chunk = blockIdx.x & 63;
    int b = bm / 5;
    int d = threadIdx.x & 63;
    int g = threadIdx.x >> 6;   // wave id 0..3
    int n0 = chunk * 256 + g * 64;
    const float* fb = feat + (size_t)b * N_ * D_;
    const float* mk = masks + (size_t)bm * N_;
    float acc = 0.f;
    float mxv = -1e30f;
    for (int i = 0; i < 64; ++i) {
        int n = n0 + i;
        float mv = mk[n];                       // uniform per wave -> broadcast
        acc = fmaf(fb[(size_t)n * D_ + d], mv, acc);
        mxv = fmaxf(mxv, mv);
    }
    __shared__ float lds[4][64];
    __shared__ float lmx[4];
    lds[g][d] = acc;
    if (d == 0) lmx[g] = mxv;
    __syncthreads();
    if (g == 0) {
        float s = lds[0][d] + lds[1][d] + lds[2][d] + lds[3][d];
        part[(size_t)blockIdx.x * 64 + d] = s;
        if (d == 0)
            maxpart[blockIdx.x] = fmaxf(fmaxf(lmx[0], lmx[1]), fmaxf(lmx[2], lmx[3]));
    }
}

// ---------- final: sum chunks, normalize over m-axis, scores ----------
__global__ void k_nffinal(const float* __restrict__ part, const float* __restrict__ maxpart,
                          float* __restrict__ out) {
    int b = blockIdx.x;     // 4 blocks
    int d = threadIdx.x;    // 64 threads
    float v[5];
    float ss = 0.f;
    for (int m = 0; m < 5; ++m) {
        int bm = b * 5 + m;
        float s = 0.f;
        for (int c = 0; c < 64; ++c) s += part[(size_t)(bm * 64 + c) * 64 + d];
        v[m] = s;
        ss += s * s;
    }
    float nrm = fmaxf(sqrtf(ss), 1e-12f);
    for (int m = 0; m < 5; ++m) out[((size_t)b * 5 + m) * 64 + d] = v[m] / nrm;
    if (d < 5) {
        int bm = b * 5 + d;
        float mx = -1e30f;
        for (int c = 0; c < 64; ++c) mx = fmaxf(mx, maxpart[bm * 64 + c]);
        out[OFF_SCORES + bm] = mx;
    }
}

extern "C" void kernel_launch(void* const* d_in, const int* in_sizes, int n_in,
                              void* d_out, int out_size, void* d_ws, size_t ws_size,
                              hipStream_t stream) {
    const float* feat  = (const float*)d_in[0];   // (4,16384,64)
    const int*   edges = (const int*)d_in[1];     // (4,2,131072)
    const float* wts   = (const float*)d_in[2];   // (4,131072)
    const float* init  = (const float*)d_in[3];   // (4,16384,128)
    float* out = (float*)d_out;

    // workspace layout (bf16 h: 65536 rows x 64 uints = 16 MB each)
    unsigned* hA = (unsigned*)d_ws;
    unsigned* hB = hA + (size_t)BN * 64;
    int* row_start  = (int*)(hB + (size_t)BN * 64);   // 65537 (+pad)
    int* cursor     = row_start + 65544;              // 65536
    int* deg        = cursor + BN;                    // 65536
    int* blockSums  = deg + BN;                       // 256
    int2* cw        = (int2*)(blockSums + 256);       // PAD_CAP int2 (~5.8 MB)
    float* part     = (float*)(cw + PAD_CAP);         // 20*64*64 = 81920
    float* maxpart  = part + 81920;                   // 1280

    // CSR build (padded rows, interleaved (col,w) pairs; padding written by k_sort)
    hipMemsetAsync(deg, 0, BN * sizeof(int), stream);
    k_count<<<TOTE / 256, 256, 0, stream>>>(edges, wts, deg);
    k_scan1<<<256, 256, 0, stream>>>(deg, blockSums);
    k_scan3<<<256, 256, 0, stream>>>(deg, blockSums, row_start, cursor);
    k_scatter<<<TOTE / 256, 256, 0, stream>>>(edges, wts, cursor, cw);
    k_sort<<<BN / 256, 256, 0, stream>>>(row_start, deg, cw);

    // 25 propagation iterations; iter 0 reads f32 init directly
    k_prop<true><<<BN / 8, 256, 0, stream>>>(init, hA, row_start, cw);
    const unsigned* src = hA;
    for (int it = 1; it < ITERS; ++it) {
        unsigned* dst = (it & 1) ? hB : hA;
        k_prop<false><<<BN / 8, 256, 0, stream>>>(src, dst, row_start, cw);
        src = dst;
    }

    // competition + outputs
    k_masks<<<BN / 4, 256, 0, stream>>>(src, out + OFF_MASKS);
    k_nfpart<<<20 * 64, 256, 0, stream>>>(feat, out + OFF_MASKS, part, maxpart);
    k_nffinal<<<4, 64, 0, stream>>>(part, maxpart, out);
}